// Round 2
// baseline (8073.418 us; speedup 1.0000x reference)
//
#include <hip/hip_runtime.h>

// Problem constants (from reference)
#define NN 50000
#define NE 160000
// dims: F_IN=1022, H1=1024, H2=512, UH=75, OUT=11
// NOTE: harness stages ALL integer inputs as int32 (see contract), so
// edge_index (int64 in the reference) arrives as const int*.

// ---------------------------------------------------------------------------
// small utility kernels
// ---------------------------------------------------------------------------
__global__ void zero_int_kernel(int* __restrict__ p, int n) {
    int i = blockIdx.x * 256 + threadIdx.x;
    if (i < n) p[i] = 0;
}

__global__ void init_deg_kernel(float* __restrict__ deg) {
    int i = blockIdx.x * 256 + threadIdx.x;
    if (i < NN) deg[i] = 1.0f;  // self-loop contributes 1
}

__global__ void hist_kernel(const int* __restrict__ ei,
                            float* __restrict__ deg, int* __restrict__ cnt) {
    int e = blockIdx.x * 256 + threadIdx.x;
    if (e < NE) {
        int d = ei[NE + e];  // dst row
        atomicAdd(&deg[d], 1.0f);
        atomicAdd(&cnt[d], 1);
    }
}

__global__ void dinv_kernel(float* __restrict__ deg) {
    int i = blockIdx.x * 256 + threadIdx.x;
    if (i < NN) deg[i] = rsqrtf(deg[i]);  // in-place deg -> d^-1/2
}

// single-block scan: row_ptr[0..N] from cnt[0..N-1]
__global__ void scan_kernel(const int* __restrict__ cnt, int* __restrict__ row_ptr) {
    __shared__ int sdata[1024];
    int carry = 0;
    if (threadIdx.x == 0) row_ptr[0] = 0;
    for (int base = 0; base < NN; base += 1024) {
        int i = base + (int)threadIdx.x;
        int v = (i < NN) ? cnt[i] : 0;
        sdata[threadIdx.x] = v;
        __syncthreads();
        for (int off = 1; off < 1024; off <<= 1) {
            int t = (threadIdx.x >= (unsigned)off) ? sdata[threadIdx.x - off] : 0;
            __syncthreads();
            sdata[threadIdx.x] += t;
            __syncthreads();
        }
        if (i < NN) row_ptr[i + 1] = carry + sdata[threadIdx.x];
        carry += sdata[1023];
        __syncthreads();
    }
}

__global__ void fill_kernel(const int* __restrict__ ei,
                            const int* __restrict__ row_ptr,
                            int* __restrict__ cnt, int* __restrict__ col_src) {
    int e = blockIdx.x * 256 + threadIdx.x;
    if (e < NE) {
        int s = ei[e];
        int d = ei[NE + e];
        int pos = row_ptr[d] + atomicAdd(&cnt[d], 1);
        col_src[pos] = s;
    }
}

// ---------------------------------------------------------------------------
// fp32 SGEMM: C[M,N] = A[M,K] @ B[K,N] (+bias,+relu per EPI)
// 128x128 tile, BK=16, 256 threads, 8x8 microtile. lda/ldb/ldc in floats.
// EPI: 0 = none, 1 = bias+relu, 2 = bias
// ---------------------------------------------------------------------------
template <int EPI>
__global__ __launch_bounds__(256) void sgemm_kernel(
    const float* __restrict__ A, int lda,
    const float* __restrict__ B, int ldb,
    const float* __restrict__ bias,
    float* __restrict__ C, int ldc,
    int M, int K, int N) {
    __shared__ float As[16 * 132];  // [k][m], padded
    __shared__ float Bs[16 * 132];  // [k][n], padded

    const int bm = blockIdx.x * 128;
    const int bn = blockIdx.y * 128;
    const int tid = (int)threadIdx.x;
    const int tm = tid >> 4;   // 0..15
    const int tn = tid & 15;   // 0..15

    float acc[8][8];
#pragma unroll
    for (int i = 0; i < 8; ++i)
#pragma unroll
        for (int j = 0; j < 8; ++j) acc[i][j] = 0.f;

    const int akk = tid & 15;   // k index for A loads
    const int ar0 = tid >> 4;   // base row for A loads
    const int bcol = tid & 127; // col for B loads
    const int bkr0 = tid >> 7;  // base k-row for B loads

    for (int k0 = 0; k0 < K; k0 += 16) {
        __syncthreads();
        // load A tile: 128 rows x 16 k (scalar, coalesced over k)
#pragma unroll
        for (int p = 0; p < 8; ++p) {
            int row = ar0 + p * 16;
            int grow = bm + row;
            int gk = k0 + akk;
            float v = (grow < M && gk < K) ? A[(size_t)grow * lda + gk] : 0.f;
            As[akk * 132 + row] = v;
        }
        // load B tile: 16 k x 128 cols (scalar, coalesced over cols)
#pragma unroll
        for (int p = 0; p < 8; ++p) {
            int krow = bkr0 + p * 2;
            int gk = k0 + krow;
            int gcol = bn + bcol;
            float v = (gk < K && gcol < N) ? B[(size_t)gk * ldb + gcol] : 0.f;
            Bs[krow * 132 + bcol] = v;
        }
        __syncthreads();
#pragma unroll
        for (int kk = 0; kk < 16; ++kk) {
            float a[8], b[8];
            *(float4*)&a[0] = *(const float4*)&As[kk * 132 + tm * 8];
            *(float4*)&a[4] = *(const float4*)&As[kk * 132 + tm * 8 + 4];
            *(float4*)&b[0] = *(const float4*)&Bs[kk * 132 + tn * 8];
            *(float4*)&b[4] = *(const float4*)&Bs[kk * 132 + tn * 8 + 4];
#pragma unroll
            for (int i = 0; i < 8; ++i)
#pragma unroll
                for (int j = 0; j < 8; ++j)
                    acc[i][j] = fmaf(a[i], b[j], acc[i][j]);
        }
    }

#pragma unroll
    for (int i = 0; i < 8; ++i) {
        int r = bm + tm * 8 + i;
        if (r >= M) continue;
#pragma unroll
        for (int j = 0; j < 8; ++j) {
            int c = bn + tn * 8 + j;
            if (c >= N) continue;
            float v = acc[i][j];
            if (EPI >= 1) v += bias[c];
            if (EPI == 1) v = fmaxf(v, 0.f);
            C[(size_t)r * ldc + c] = v;
        }
    }
}

// ---------------------------------------------------------------------------
// CSR aggregation over H=512 columns:
// out[i] = relu( sum_{e: dst=i} tmp[src_e]*dinv[src]*dinv[i]
//                + tmp[i]*dinv[i]^2 + bias )
// tmp is NN x 512 contiguous; out has row stride ld_out (floats).
// one wave (64 lanes) per node, 2 x float4 per lane
// ---------------------------------------------------------------------------
__global__ __launch_bounds__(256) void agg512_kernel(
    const float* __restrict__ tmp, const float* __restrict__ dinv,
    const int* __restrict__ row_ptr, const int* __restrict__ col_src,
    const float* __restrict__ bias, float* __restrict__ outp, int ld_out) {
    const int wid = (blockIdx.x * 256 + (int)threadIdx.x) >> 6;  // node
    const int lane = (int)threadIdx.x & 63;
    if (wid >= NN) return;
    const float4* t4 = (const float4*)tmp;

    float di = dinv[wid];
    float wself = di * di;
    float4 acc[2];
    const float4* selfrow = t4 + (size_t)wid * 128;
#pragma unroll
    for (int v = 0; v < 2; ++v) {
        float4 x = selfrow[lane + 64 * v];
        acc[v].x = x.x * wself; acc[v].y = x.y * wself;
        acc[v].z = x.z * wself; acc[v].w = x.w * wself;
    }
    const int e0 = row_ptr[wid], e1 = row_ptr[wid + 1];
    for (int e = e0; e < e1; ++e) {
        int s = col_src[e];
        float w = dinv[s] * di;
        const float4* r = t4 + (size_t)s * 128;
#pragma unroll
        for (int v = 0; v < 2; ++v) {
            float4 x = r[lane + 64 * v];
            acc[v].x = fmaf(x.x, w, acc[v].x);
            acc[v].y = fmaf(x.y, w, acc[v].y);
            acc[v].z = fmaf(x.z, w, acc[v].z);
            acc[v].w = fmaf(x.w, w, acc[v].w);
        }
    }
    const float4* b4 = (const float4*)bias;
    float4* o4 = (float4*)(outp + (size_t)wid * ld_out);
#pragma unroll
    for (int v = 0; v < 2; ++v) {
        float4 b = b4[lane + 64 * v];
        float4 r;
        r.x = fmaxf(acc[v].x + b.x, 0.f);
        r.y = fmaxf(acc[v].y + b.y, 0.f);
        r.z = fmaxf(acc[v].z + b.z, 0.f);
        r.w = fmaxf(acc[v].w + b.w, 0.f);
        o4[lane + 64 * v] = r;
    }
}

// ---------------------------------------------------------------------------
// launch
// ---------------------------------------------------------------------------
static inline size_t ws_align(size_t x) { return (x + 255) & ~(size_t)255; }

extern "C" void kernel_launch(void* const* d_in, const int* in_sizes, int n_in,
                              void* d_out, int out_size, void* d_ws, size_t ws_size,
                              hipStream_t stream) {
    const float* x  = (const float*)d_in[0];
    const int* ei   = (const int*)d_in[1];   // int inputs staged as int32
    const float* W1 = (const float*)d_in[2];  const float* b1 = (const float*)d_in[3];
    const float* W2 = (const float*)d_in[4];  const float* b2 = (const float*)d_in[5];
    const float* W3 = (const float*)d_in[6];  const float* b3 = (const float*)d_in[7];
    const float* W4 = (const float*)d_in[8];  const float* b4 = (const float*)d_in[9];
    const float* W5 = (const float*)d_in[10]; const float* b5 = (const float*)d_in[11];
    const float* Uw1 = (const float*)d_in[12]; const float* Ub1 = (const float*)d_in[13];
    const float* Uw2 = (const float*)d_in[14]; const float* Ub2 = (const float*)d_in[15];
    float* out = (float*)d_out;

    // workspace layout (~308 MB peak)
    char* ws = (char*)d_ws;
    float* dinv   = (float*)ws; ws += ws_align((size_t)NN * 4);
    int* cnt      = (int*)ws;   ws += ws_align((size_t)NN * 4);
    int* row_ptr  = (int*)ws;   ws += ws_align((size_t)(NN + 1) * 4);
    int* col_src  = (int*)ws;   ws += ws_align((size_t)NE * 4);
    float* h1big  = (float*)ws; ws += (size_t)NN * 1024 * 4;  // layer-1 out; later hA/hB
    float* tmp    = (float*)ws;                               // NN x 512 gemm scratch
    float* hA = h1big;                     // NN x 512 (aliases h1big after L2 gemm)
    float* hB = h1big + (size_t)NN * 512;  // NN x 512

    const int nb_n = (NN + 255) / 256;   // node-grid
    const int nb_e = (NE + 255) / 256;   // edge-grid

    // CSR + norm build (per call; deterministic)
    zero_int_kernel<<<nb_n, 256, 0, stream>>>(cnt, NN);
    init_deg_kernel<<<nb_n, 256, 0, stream>>>(dinv);
    hist_kernel<<<nb_e, 256, 0, stream>>>(ei, dinv, cnt);
    dinv_kernel<<<nb_n, 256, 0, stream>>>(dinv);
    scan_kernel<<<1, 1024, 0, stream>>>(cnt, row_ptr);
    zero_int_kernel<<<nb_n, 256, 0, stream>>>(cnt, NN);
    fill_kernel<<<nb_e, 256, 0, stream>>>(ei, row_ptr, cnt, col_src);

    const int gm = (NN + 127) / 128;       // 391
    const int agg_blocks = (NN + 3) / 4;   // 4 waves/block

    // L1 (K=1022 -> H1=1024), two 512-column blocks to cap workspace
    for (int c = 0; c < 2; ++c) {
        sgemm_kernel<0><<<dim3(gm, 4), 256, 0, stream>>>(
            x, 1022, W1 + c * 512, 1024, nullptr, tmp, 512, NN, 1022, 512);
        agg512_kernel<<<agg_blocks, 256, 0, stream>>>(
            tmp, dinv, row_ptr, col_src, b1 + c * 512, h1big + c * 512, 1024);
    }
    // L2 (K=1024 -> 512); h1big consumed by gemm, then hA overwrites its base
    sgemm_kernel<0><<<dim3(gm, 4), 256, 0, stream>>>(
        h1big, 1024, W2, 512, nullptr, tmp, 512, NN, 1024, 512);
    agg512_kernel<<<agg_blocks, 256, 0, stream>>>(
        tmp, dinv, row_ptr, col_src, b2, hA, 512);
    // L3
    sgemm_kernel<0><<<dim3(gm, 4), 256, 0, stream>>>(
        hA, 512, W3, 512, nullptr, tmp, 512, NN, 512, 512);
    agg512_kernel<<<agg_blocks, 256, 0, stream>>>(
        tmp, dinv, row_ptr, col_src, b3, hB, 512);
    // L4
    sgemm_kernel<0><<<dim3(gm, 4), 256, 0, stream>>>(
        hB, 512, W4, 512, nullptr, tmp, 512, NN, 512, 512);
    agg512_kernel<<<agg_blocks, 256, 0, stream>>>(
        tmp, dinv, row_ptr, col_src, b4, hA, 512);
    // L5
    sgemm_kernel<0><<<dim3(gm, 4), 256, 0, stream>>>(
        hA, 512, W5, 512, nullptr, tmp, 512, NN, 512, 512);
    agg512_kernel<<<agg_blocks, 256, 0, stream>>>(
        tmp, dinv, row_ptr, col_src, b5, hB, 512);
    // head1: relu(hB @ Uw1 + Ub1) -> tmp (NN x 75)
    sgemm_kernel<1><<<dim3(gm, 1), 256, 0, stream>>>(
        hB, 512, Uw1, 75, Ub1, tmp, 75, NN, 512, 75);
    // head2: tmp @ Uw2 + Ub2 -> out (NN x 11)
    sgemm_kernel<2><<<dim3(gm, 1), 256, 0, stream>>>(
        tmp, 75, Uw2, 11, Ub2, out, 11, NN, 75, 11);
}

// Round 3
// 2685.028 us; speedup vs baseline: 3.0068x; 3.0068x over previous
//
#include <hip/hip_runtime.h>

// Problem constants (from reference)
#define NN 50000
#define NE 160000
// dims: F_IN=1022, H1=1024, H2=512, UH=75, OUT=11
// NOTE: harness stages ALL integer inputs as int32, so edge_index arrives
// as const int* (2*NE int32s).

typedef _Float16 f16v4 __attribute__((ext_vector_type(4)));
typedef _Float16 f16v8 __attribute__((ext_vector_type(8)));
typedef float f32v4 __attribute__((ext_vector_type(4)));

// ---------------------------------------------------------------------------
// small utility kernels
// ---------------------------------------------------------------------------
__global__ void zero_int_kernel(int* __restrict__ p, int n) {
    int i = blockIdx.x * 256 + threadIdx.x;
    if (i < n) p[i] = 0;
}

__global__ void init_deg_kernel(float* __restrict__ deg) {
    int i = blockIdx.x * 256 + threadIdx.x;
    if (i < NN) deg[i] = 1.0f;  // self-loop contributes 1
}

__global__ void hist_kernel(const int* __restrict__ ei,
                            float* __restrict__ deg, int* __restrict__ cnt) {
    int e = blockIdx.x * 256 + threadIdx.x;
    if (e < NE) {
        int d = ei[NE + e];  // dst row
        atomicAdd(&deg[d], 1.0f);
        atomicAdd(&cnt[d], 1);
    }
}

__global__ void dinv_kernel(float* __restrict__ deg) {
    int i = blockIdx.x * 256 + threadIdx.x;
    if (i < NN) deg[i] = rsqrtf(deg[i]);  // in-place deg -> d^-1/2
}

// single-block scan: row_ptr[0..N] from cnt[0..N-1]
__global__ void scan_kernel(const int* __restrict__ cnt, int* __restrict__ row_ptr) {
    __shared__ int sdata[1024];
    int carry = 0;
    if (threadIdx.x == 0) row_ptr[0] = 0;
    for (int base = 0; base < NN; base += 1024) {
        int i = base + (int)threadIdx.x;
        int v = (i < NN) ? cnt[i] : 0;
        sdata[threadIdx.x] = v;
        __syncthreads();
        for (int off = 1; off < 1024; off <<= 1) {
            int t = (threadIdx.x >= (unsigned)off) ? sdata[threadIdx.x - off] : 0;
            __syncthreads();
            sdata[threadIdx.x] += t;
            __syncthreads();
        }
        if (i < NN) row_ptr[i + 1] = carry + sdata[threadIdx.x];
        carry += sdata[1023];
        __syncthreads();
    }
}

__global__ void fill_kernel(const int* __restrict__ ei,
                            const int* __restrict__ row_ptr,
                            int* __restrict__ cnt, int* __restrict__ col_src) {
    int e = blockIdx.x * 256 + threadIdx.x;
    if (e < NE) {
        int s = ei[e];
        int d = ei[NE + e];
        int pos = row_ptr[d] + atomicAdd(&cnt[d], 1);
        col_src[pos] = s;
    }
}

// W [K,N] row-major  ->  Wt hi/lo f16 [N,Kpad] row-major, zero-padded K..Kpad
__global__ void wsplit_kernel(const float* __restrict__ W,
                              _Float16* __restrict__ hi, _Float16* __restrict__ lo,
                              int K, int N, int Kpad) {
    int t = blockIdx.x * 256 + threadIdx.x;
    if (t >= N * Kpad) return;
    int n = t / Kpad, k = t - n * Kpad;
    float v = (k < K) ? W[(size_t)k * N + n] : 0.f;
    _Float16 h = (_Float16)v;
    hi[t] = h;
    lo[t] = (_Float16)(v - (float)h);
}

// ---------------------------------------------------------------------------
// Split-f16 MFMA GEMM: C[M,512] = A[M,K](fp32) @ B[K,512]
// B pre-split/transposed: Bhi/Blo f16 [128*4 cols][ldk], k contiguous.
// A reg-staged fp32 -> hi/lo f16 in LDS. 128x128 tile, BK=32, 4 waves,
// wave = 64x64 out = 4x4 frags of 16x16x32, 3 MFMA per frag pair.
// ---------------------------------------------------------------------------
#define STR 40  // LDS row stride in halves (bank-spread padding)

__global__ __launch_bounds__(256) void mfma_gemm_kernel(
    const float* __restrict__ A, int lda,
    const _Float16* __restrict__ Bhi, const _Float16* __restrict__ Blo, int ldk,
    float* __restrict__ C, int ldc, int M, int K) {
    __shared__ __align__(16) _Float16 AsH[128 * STR];
    __shared__ __align__(16) _Float16 AsL[128 * STR];
    __shared__ __align__(16) _Float16 BsH[128 * STR];
    __shared__ __align__(16) _Float16 BsL[128 * STR];

    const int tid = (int)threadIdx.x;
    const int lane = tid & 63, wave = tid >> 6;
    const int wm = wave >> 1, wn = wave & 1;
    const int lrow = lane & 15, kgrp = lane >> 4;
    const int bm = blockIdx.x * 128, bn = blockIdx.y * 128;

    f32v4 acc[4][4];
    const f32v4 zero4 = {0.f, 0.f, 0.f, 0.f};
#pragma unroll
    for (int i = 0; i < 4; ++i)
#pragma unroll
        for (int j = 0; j < 4; ++j) acc[i][j] = zero4;

    // staging assignments
    const int a_k4 = (tid & 7) * 4;   // k offset 0..28
    const int a_row0 = tid >> 3;      // 0..31
    const int b_col = tid & 127;
    const int b_ch0 = (tid >> 7) * 2; // chunk 0 or 2

    for (int k0 = 0; k0 < K; k0 += 32) {
        __syncthreads();
        // ---- stage A: 128 rows x 32 k, fp32 -> hi/lo f16
#pragma unroll
        for (int p = 0; p < 4; ++p) {
            int row = a_row0 + p * 32;
            int gr = bm + row;
            float v0 = 0.f, v1 = 0.f, v2 = 0.f, v3 = 0.f;
            if (gr < M) {
                const float* src = A + (size_t)gr * lda + k0 + a_k4;
                if (k0 + a_k4 + 4 <= K) {
                    float2 u0 = *(const float2*)(src);
                    float2 u1 = *(const float2*)(src + 2);
                    v0 = u0.x; v1 = u0.y; v2 = u1.x; v3 = u1.y;
                } else {
                    if (k0 + a_k4 + 0 < K) v0 = src[0];
                    if (k0 + a_k4 + 1 < K) v1 = src[1];
                    if (k0 + a_k4 + 2 < K) v2 = src[2];
                    if (k0 + a_k4 + 3 < K) v3 = src[3];
                }
            }
            f16v4 hv, lv;
            _Float16 h;
            h = (_Float16)v0; hv[0] = h; lv[0] = (_Float16)(v0 - (float)h);
            h = (_Float16)v1; hv[1] = h; lv[1] = (_Float16)(v1 - (float)h);
            h = (_Float16)v2; hv[2] = h; lv[2] = (_Float16)(v2 - (float)h);
            h = (_Float16)v3; hv[3] = h; lv[3] = (_Float16)(v3 - (float)h);
            *(f16v4*)&AsH[row * STR + a_k4] = hv;
            *(f16v4*)&AsL[row * STR + a_k4] = lv;
        }
        // ---- stage B: 128 cols x 32 k, already f16 (Kpad-padded, no guards)
#pragma unroll
        for (int cc = 0; cc < 2; ++cc) {
            int kh = (b_ch0 + cc) * 8;
            const size_t boff = (size_t)(bn + b_col) * ldk + k0 + kh;
            int4 hsrc = *(const int4*)(Bhi + boff);
            int4 lsrc = *(const int4*)(Blo + boff);
            *(int4*)&BsH[b_col * STR + kh] = hsrc;
            *(int4*)&BsL[b_col * STR + kh] = lsrc;
        }
        __syncthreads();

        // ---- fragments + MFMA
        f16v8 ah[4], al[4];
#pragma unroll
        for (int i = 0; i < 4; ++i) {
            int r = wm * 64 + i * 16 + lrow;
            ah[i] = *(const f16v8*)&AsH[r * STR + kgrp * 8];
            al[i] = *(const f16v8*)&AsL[r * STR + kgrp * 8];
        }
#pragma unroll
        for (int j = 0; j < 4; ++j) {
            int c = wn * 64 + j * 16 + lrow;
            f16v8 bh = *(const f16v8*)&BsH[c * STR + kgrp * 8];
            f16v8 bl = *(const f16v8*)&BsL[c * STR + kgrp * 8];
#pragma unroll
            for (int i = 0; i < 4; ++i) {
                acc[i][j] = __builtin_amdgcn_mfma_f32_16x16x32_f16(ah[i], bh, acc[i][j], 0, 0, 0);
                acc[i][j] = __builtin_amdgcn_mfma_f32_16x16x32_f16(ah[i], bl, acc[i][j], 0, 0, 0);
                acc[i][j] = __builtin_amdgcn_mfma_f32_16x16x32_f16(al[i], bh, acc[i][j], 0, 0, 0);
            }
        }
    }

    // ---- epilogue: D row = (lane>>4)*4 + reg, col = lane&15 within 16x16 frag
#pragma unroll
    for (int i = 0; i < 4; ++i) {
#pragma unroll
        for (int r = 0; r < 4; ++r) {
            int grow = bm + wm * 64 + i * 16 + kgrp * 4 + r;
            if (grow >= M) continue;
            float* dst = C + (size_t)grow * ldc + bn + wn * 64 + lrow;
#pragma unroll
            for (int j = 0; j < 4; ++j) dst[j * 16] = acc[i][j][r];
        }
    }
}

// ---------------------------------------------------------------------------
// fp32 SGEMM (kept for the two small head GEMMs). EPI: 1 = bias+relu, 2 = bias
// ---------------------------------------------------------------------------
template <int EPI>
__global__ __launch_bounds__(256) void sgemm_kernel(
    const float* __restrict__ A, int lda,
    const float* __restrict__ B, int ldb,
    const float* __restrict__ bias,
    float* __restrict__ C, int ldc,
    int M, int K, int N) {
    __shared__ float As[16 * 132];
    __shared__ float Bs[16 * 132];

    const int bm = blockIdx.x * 128;
    const int bn = blockIdx.y * 128;
    const int tid = (int)threadIdx.x;
    const int tm = tid >> 4;
    const int tn = tid & 15;

    float acc[8][8];
#pragma unroll
    for (int i = 0; i < 8; ++i)
#pragma unroll
        for (int j = 0; j < 8; ++j) acc[i][j] = 0.f;

    const int akk = tid & 15;
    const int ar0 = tid >> 4;
    const int bcol = tid & 127;
    const int bkr0 = tid >> 7;

    for (int k0 = 0; k0 < K; k0 += 16) {
        __syncthreads();
#pragma unroll
        for (int p = 0; p < 8; ++p) {
            int row = ar0 + p * 16;
            int grow = bm + row;
            int gk = k0 + akk;
            float v = (grow < M && gk < K) ? A[(size_t)grow * lda + gk] : 0.f;
            As[akk * 132 + row] = v;
        }
#pragma unroll
        for (int p = 0; p < 8; ++p) {
            int krow = bkr0 + p * 2;
            int gk = k0 + krow;
            int gcol = bn + bcol;
            float v = (gk < K && gcol < N) ? B[(size_t)gk * ldb + gcol] : 0.f;
            Bs[krow * 132 + bcol] = v;
        }
        __syncthreads();
#pragma unroll
        for (int kk = 0; kk < 16; ++kk) {
            float a[8], b[8];
            *(float4*)&a[0] = *(const float4*)&As[kk * 132 + tm * 8];
            *(float4*)&a[4] = *(const float4*)&As[kk * 132 + tm * 8 + 4];
            *(float4*)&b[0] = *(const float4*)&Bs[kk * 132 + tn * 8];
            *(float4*)&b[4] = *(const float4*)&Bs[kk * 132 + tn * 8 + 4];
#pragma unroll
            for (int i = 0; i < 8; ++i)
#pragma unroll
                for (int j = 0; j < 8; ++j)
                    acc[i][j] = fmaf(a[i], b[j], acc[i][j]);
        }
    }

#pragma unroll
    for (int i = 0; i < 8; ++i) {
        int r = bm + tm * 8 + i;
        if (r >= M) continue;
#pragma unroll
        for (int j = 0; j < 8; ++j) {
            int c = bn + tn * 8 + j;
            if (c >= N) continue;
            float v = acc[i][j];
            if (EPI >= 1) v += bias[c];
            if (EPI == 1) v = fmaxf(v, 0.f);
            C[(size_t)r * ldc + c] = v;
        }
    }
}

// ---------------------------------------------------------------------------
// CSR aggregation over 512 cols: out = relu(agg + bias); one wave per node
// ---------------------------------------------------------------------------
__global__ __launch_bounds__(256) void agg512_kernel(
    const float* __restrict__ tmp, const float* __restrict__ dinv,
    const int* __restrict__ row_ptr, const int* __restrict__ col_src,
    const float* __restrict__ bias, float* __restrict__ outp, int ld_out) {
    const int wid = (blockIdx.x * 256 + (int)threadIdx.x) >> 6;
    const int lane = (int)threadIdx.x & 63;
    if (wid >= NN) return;
    const float4* t4 = (const float4*)tmp;

    float di = dinv[wid];
    float wself = di * di;
    float4 acc[2];
    const float4* selfrow = t4 + (size_t)wid * 128;
#pragma unroll
    for (int v = 0; v < 2; ++v) {
        float4 x = selfrow[lane + 64 * v];
        acc[v].x = x.x * wself; acc[v].y = x.y * wself;
        acc[v].z = x.z * wself; acc[v].w = x.w * wself;
    }
    const int e0 = row_ptr[wid], e1 = row_ptr[wid + 1];
    for (int e = e0; e < e1; ++e) {
        int s = col_src[e];
        float w = dinv[s] * di;
        const float4* r = t4 + (size_t)s * 128;
#pragma unroll
        for (int v = 0; v < 2; ++v) {
            float4 x = r[lane + 64 * v];
            acc[v].x = fmaf(x.x, w, acc[v].x);
            acc[v].y = fmaf(x.y, w, acc[v].y);
            acc[v].z = fmaf(x.z, w, acc[v].z);
            acc[v].w = fmaf(x.w, w, acc[v].w);
        }
    }
    const float4* b4 = (const float4*)bias;
    float4* o4 = (float4*)(outp + (size_t)wid * ld_out);
#pragma unroll
    for (int v = 0; v < 2; ++v) {
        float4 b = b4[lane + 64 * v];
        float4 r;
        r.x = fmaxf(acc[v].x + b.x, 0.f);
        r.y = fmaxf(acc[v].y + b.y, 0.f);
        r.z = fmaxf(acc[v].z + b.z, 0.f);
        r.w = fmaxf(acc[v].w + b.w, 0.f);
        o4[lane + 64 * v] = r;
    }
}

// ---------------------------------------------------------------------------
// launch
// ---------------------------------------------------------------------------
static inline size_t ws_align(size_t x) { return (x + 255) & ~(size_t)255; }

extern "C" void kernel_launch(void* const* d_in, const int* in_sizes, int n_in,
                              void* d_out, int out_size, void* d_ws, size_t ws_size,
                              hipStream_t stream) {
    const float* x  = (const float*)d_in[0];
    const int* ei   = (const int*)d_in[1];
    const float* W1 = (const float*)d_in[2];  const float* b1 = (const float*)d_in[3];
    const float* W2 = (const float*)d_in[4];  const float* b2 = (const float*)d_in[5];
    const float* W3 = (const float*)d_in[6];  const float* b3 = (const float*)d_in[7];
    const float* W4 = (const float*)d_in[8];  const float* b4 = (const float*)d_in[9];
    const float* W5 = (const float*)d_in[10]; const float* b5 = (const float*)d_in[11];
    const float* Uw1 = (const float*)d_in[12]; const float* Ub1 = (const float*)d_in[13];
    const float* Uw2 = (const float*)d_in[14]; const float* Ub2 = (const float*)d_in[15];
    float* out = (float*)d_out;

    // workspace layout (~318 MB peak; round-2's 308 MB layout + 9 MB weights)
    char* ws = (char*)d_ws;
    float* dinv   = (float*)ws; ws += ws_align((size_t)NN * 4);
    int* cnt      = (int*)ws;   ws += ws_align((size_t)NN * 4);
    int* row_ptr  = (int*)ws;   ws += ws_align((size_t)(NN + 1) * 4);
    int* col_src  = (int*)ws;   ws += ws_align((size_t)NE * 4);
    _Float16* w1h = (_Float16*)ws; ws += ws_align((size_t)1024 * 1024 * 2);
    _Float16* w1l = (_Float16*)ws; ws += ws_align((size_t)1024 * 1024 * 2);
    _Float16* w2h = (_Float16*)ws; ws += ws_align((size_t)512 * 1024 * 2);
    _Float16* w2l = (_Float16*)ws; ws += ws_align((size_t)512 * 1024 * 2);
    _Float16* w3h = (_Float16*)ws; ws += ws_align((size_t)512 * 512 * 2);
    _Float16* w3l = (_Float16*)ws; ws += ws_align((size_t)512 * 512 * 2);
    _Float16* w4h = (_Float16*)ws; ws += ws_align((size_t)512 * 512 * 2);
    _Float16* w4l = (_Float16*)ws; ws += ws_align((size_t)512 * 512 * 2);
    _Float16* w5h = (_Float16*)ws; ws += ws_align((size_t)512 * 512 * 2);
    _Float16* w5l = (_Float16*)ws; ws += ws_align((size_t)512 * 512 * 2);
    float* h1big  = (float*)ws; ws += (size_t)NN * 1024 * 4;  // L1 out; later hA/hB
    float* tmp    = (float*)ws;                               // NN x 512 gemm scratch
    float* hA = h1big;
    float* hB = h1big + (size_t)NN * 512;

    const int nb_n = (NN + 255) / 256;
    const int nb_e = (NE + 255) / 256;

    // CSR + norm build
    zero_int_kernel<<<nb_n, 256, 0, stream>>>(cnt, NN);
    init_deg_kernel<<<nb_n, 256, 0, stream>>>(dinv);
    hist_kernel<<<nb_e, 256, 0, stream>>>(ei, dinv, cnt);
    dinv_kernel<<<nb_n, 256, 0, stream>>>(dinv);
    scan_kernel<<<1, 1024, 0, stream>>>(cnt, row_ptr);
    zero_int_kernel<<<nb_n, 256, 0, stream>>>(cnt, NN);
    fill_kernel<<<nb_e, 256, 0, stream>>>(ei, row_ptr, cnt, col_src);

    // weight transpose + split (tiny)
    wsplit_kernel<<<(1024 * 1024 + 255) / 256, 256, 0, stream>>>(W1, w1h, w1l, 1022, 1024, 1024);
    wsplit_kernel<<<(512 * 1024 + 255) / 256, 256, 0, stream>>>(W2, w2h, w2l, 1024, 512, 1024);
    wsplit_kernel<<<(512 * 512 + 255) / 256, 256, 0, stream>>>(W3, w3h, w3l, 512, 512, 512);
    wsplit_kernel<<<(512 * 512 + 255) / 256, 256, 0, stream>>>(W4, w4h, w4l, 512, 512, 512);
    wsplit_kernel<<<(512 * 512 + 255) / 256, 256, 0, stream>>>(W5, w5h, w5l, 512, 512, 512);

    const int gm = (NN + 127) / 128;       // 391
    const dim3 ggrid(gm, 4);               // N = 512 per GEMM
    const int agg_blocks = (NN + 3) / 4;   // 4 waves/block

    // L1 (K=1022 -> H1=1024) in two 512-col blocks
    for (int c = 0; c < 2; ++c) {
        mfma_gemm_kernel<<<ggrid, 256, 0, stream>>>(
            x, 1022, w1h + (size_t)c * 512 * 1024, w1l + (size_t)c * 512 * 1024, 1024,
            tmp, 512, NN, 1022);
        agg512_kernel<<<agg_blocks, 256, 0, stream>>>(
            tmp, dinv, row_ptr, col_src, b1 + c * 512, h1big + c * 512, 1024);
    }
    // L2 (K=1024 -> 512)
    mfma_gemm_kernel<<<ggrid, 256, 0, stream>>>(
        h1big, 1024, w2h, w2l, 1024, tmp, 512, NN, 1024);
    agg512_kernel<<<agg_blocks, 256, 0, stream>>>(
        tmp, dinv, row_ptr, col_src, b2, hA, 512);
    // L3
    mfma_gemm_kernel<<<ggrid, 256, 0, stream>>>(
        hA, 512, w3h, w3l, 512, tmp, 512, NN, 512);
    agg512_kernel<<<agg_blocks, 256, 0, stream>>>(
        tmp, dinv, row_ptr, col_src, b3, hB, 512);
    // L4
    mfma_gemm_kernel<<<ggrid, 256, 0, stream>>>(
        hB, 512, w4h, w4l, 512, tmp, 512, NN, 512);
    agg512_kernel<<<agg_blocks, 256, 0, stream>>>(
        tmp, dinv, row_ptr, col_src, b4, hA, 512);
    // L5
    mfma_gemm_kernel<<<ggrid, 256, 0, stream>>>(
        hA, 512, w5h, w5l, 512, tmp, 512, NN, 512);
    agg512_kernel<<<agg_blocks, 256, 0, stream>>>(
        tmp, dinv, row_ptr, col_src, b5, hB, 512);
    // heads (fp32 path)
    sgemm_kernel<1><<<dim3(gm, 1), 256, 0, stream>>>(
        hB, 512, Uw1, 75, Ub1, tmp, 75, NN, 512, 75);
    sgemm_kernel<2><<<dim3(gm, 1), 256, 0, stream>>>(
        tmp, 75, Uw2, 11, Ub2, out, 11, NN, 75, 11);
}

// Round 5
// 2263.540 us; speedup vs baseline: 3.5667x; 1.1862x over previous
//
#include <hip/hip_runtime.h>

// Problem constants
#define NN 50000
#define NE 160000
#define MPAD 50048   // 391 * 128
// dims: F_IN=1022(pad 1024), H1=1024, H2=512, UH=75(pad 128), OUT=11

typedef _Float16 f16v4 __attribute__((ext_vector_type(4)));
typedef _Float16 f16v8 __attribute__((ext_vector_type(8)));
typedef float f32v4 __attribute__((ext_vector_type(4)));

// ---------------------------------------------------------------------------
// async global->LDS, 16B per lane. LDS dest = wave-uniform base + lane*16.
// ---------------------------------------------------------------------------
__device__ __forceinline__ void gload16(const void* g, void* l) {
    __builtin_amdgcn_global_load_lds(
        (const __attribute__((address_space(1))) unsigned int*)g,
        (__attribute__((address_space(3))) unsigned int*)l, 16, 0, 0);
}

// bijective XCD-aware block swizzle (8 XCDs, m204 formula)
__device__ __forceinline__ int xcd_swizzle(int g, int total) {
    int q = total >> 3, r = total & 7;
    int xcd = g & 7, jj = g >> 3;
    return (xcd < r ? xcd * (q + 1) : r * (q + 1) + (xcd - r) * q) + jj;
}

// ---------------------------------------------------------------------------
// small utility kernels
// ---------------------------------------------------------------------------
__global__ void zero_int_kernel(int* __restrict__ p, int n) {
    int i = blockIdx.x * 256 + threadIdx.x;
    if (i < n) p[i] = 0;
}

__global__ void init_deg_kernel(float* __restrict__ deg) {
    int i = blockIdx.x * 256 + threadIdx.x;
    if (i < NN) deg[i] = 1.0f;
}

__global__ void hist_kernel(const int* __restrict__ ei,
                            float* __restrict__ deg, int* __restrict__ cnt) {
    int e = blockIdx.x * 256 + threadIdx.x;
    if (e < NE) {
        int d = ei[NE + e];
        atomicAdd(&deg[d], 1.0f);
        atomicAdd(&cnt[d], 1);
    }
}

__global__ void dinv_kernel(float* __restrict__ deg) {
    int i = blockIdx.x * 256 + threadIdx.x;
    if (i < NN) deg[i] = rsqrtf(deg[i]);
}

__global__ void scan_kernel(const int* __restrict__ cnt, int* __restrict__ row_ptr) {
    __shared__ int sdata[1024];
    int carry = 0;
    if (threadIdx.x == 0) row_ptr[0] = 0;
    for (int base = 0; base < NN; base += 1024) {
        int i = base + (int)threadIdx.x;
        int v = (i < NN) ? cnt[i] : 0;
        sdata[threadIdx.x] = v;
        __syncthreads();
        for (int off = 1; off < 1024; off <<= 1) {
            int t = (threadIdx.x >= (unsigned)off) ? sdata[threadIdx.x - off] : 0;
            __syncthreads();
            sdata[threadIdx.x] += t;
            __syncthreads();
        }
        if (i < NN) row_ptr[i + 1] = carry + sdata[threadIdx.x];
        carry += sdata[1023];
        __syncthreads();
    }
}

__global__ void fill_kernel(const int* __restrict__ ei,
                            const int* __restrict__ row_ptr,
                            int* __restrict__ cnt, int* __restrict__ col_src) {
    int e = blockIdx.x * 256 + threadIdx.x;
    if (e < NE) {
        int s = ei[e];
        int d = ei[NE + e];
        int pos = row_ptr[d] + atomicAdd(&cnt[d], 1);
        col_src[pos] = s;
    }
}

// W [K,N] row-major -> hi/lo f16 [Npad][Kpad], zero pad both dims
__global__ void wsplit_kernel(const float* __restrict__ W,
                              _Float16* __restrict__ hi, _Float16* __restrict__ lo,
                              int K, int N, int Kpad, int Npad) {
    int t = blockIdx.x * 256 + threadIdx.x;
    if (t >= Npad * Kpad) return;
    int n = t / Kpad, k = t - n * Kpad;
    float v = (k < K && n < N) ? W[(size_t)k * N + n] : 0.f;
    _Float16 h = (_Float16)v;
    hi[t] = h;
    lo[t] = (_Float16)(v - (float)h);
}

// ---------------------------------------------------------------------------
// Split-f16 MFMA GEMM, all-f16 inputs, global_load_lds staging.
// C[MPAD, nbn*128] = (Ah+Al)[MPAD,K] @ (Bh+Bl)^T  (3-MFMA split)
// A: [MPAD][K] f16 hi/lo row-major. B: [Npad][K] f16 hi/lo (k contiguous).
// 128x128 tile, BK=32, 4 waves (2x2), wave 64x64 = 4x4 frags 16x16x32.
// LDS layout [kgrp][row][8] halves -> conflict-free b128 reads/writes.
// EPI: 0 none; 1 bias(col<nreal)+relu.
// ---------------------------------------------------------------------------
template <int EPI>
__global__ __launch_bounds__(256, 4) void mgemm_kernel(
    const _Float16* __restrict__ Ah, const _Float16* __restrict__ Al, int lda,
    const _Float16* __restrict__ Bh, const _Float16* __restrict__ Bl,
    const float* __restrict__ bias, int nreal,
    float* __restrict__ C, int ldc, int K, int nbn) {
    __shared__ __align__(16) _Float16 sAh[4096];
    __shared__ __align__(16) _Float16 sAl[4096];
    __shared__ __align__(16) _Float16 sBh[4096];
    __shared__ __align__(16) _Float16 sBl[4096];

    const int tid = (int)threadIdx.x;
    const int lane = tid & 63, w = tid >> 6;
    const int wm = w >> 1, wn = w & 1;
    const int lrow = lane & 15, kg4 = lane >> 4;

    const int wg = xcd_swizzle((int)blockIdx.x, (int)gridDim.x);
    const int bm = (wg / nbn) * 128;
    const int bn = (wg % nbn) * 128;

    f32v4 acc[4][4];
    const f32v4 zero4 = {0.f, 0.f, 0.f, 0.f};
#pragma unroll
    for (int i = 0; i < 4; ++i)
#pragma unroll
        for (int j = 0; j < 4; ++j) acc[i][j] = zero4;

    for (int k0 = 0; k0 < K; k0 += 32) {
        __syncthreads();  // prev compute done before overwrite
#pragma unroll
        for (int p = 0; p < 2; ++p) {
            int c = p * 256 + w * 64 + lane;   // chunk 0..511
            int kg = c >> 7, rw = c & 127;
            int ub = (p * 256 + w * 64) * 8;   // wave-uniform LDS half-offset
            const size_t ao = (size_t)(bm + rw) * lda + k0 + kg * 8;
            const size_t bo = (size_t)(bn + rw) * K + k0 + kg * 8;
            gload16(Ah + ao, &sAh[ub]);
            gload16(Al + ao, &sAl[ub]);
            gload16(Bh + bo, &sBh[ub]);
            gload16(Bl + bo, &sBl[ub]);
        }
        asm volatile("s_waitcnt vmcnt(0)" ::: "memory");
        __syncthreads();

        f16v8 ah[4], al[4];
#pragma unroll
        for (int i = 0; i < 4; ++i) {
            int rr = wm * 64 + i * 16 + lrow;
            ah[i] = *(const f16v8*)&sAh[kg4 * 1024 + rr * 8];
            al[i] = *(const f16v8*)&sAl[kg4 * 1024 + rr * 8];
        }
#pragma unroll
        for (int j = 0; j < 4; ++j) {
            int cc = wn * 64 + j * 16 + lrow;
            f16v8 bh = *(const f16v8*)&sBh[kg4 * 1024 + cc * 8];
            f16v8 bl = *(const f16v8*)&sBl[kg4 * 1024 + cc * 8];
#pragma unroll
            for (int i = 0; i < 4; ++i) {
                acc[i][j] = __builtin_amdgcn_mfma_f32_16x16x32_f16(ah[i], bh, acc[i][j], 0, 0, 0);
                acc[i][j] = __builtin_amdgcn_mfma_f32_16x16x32_f16(ah[i], bl, acc[i][j], 0, 0, 0);
                acc[i][j] = __builtin_amdgcn_mfma_f32_16x16x32_f16(al[i], bh, acc[i][j], 0, 0, 0);
            }
        }
    }

    // epilogue: frag row = kg4*4 + rr, col = lrow; C rows padded (no M guard)
#pragma unroll
    for (int i = 0; i < 4; ++i) {
#pragma unroll
        for (int rr = 0; rr < 4; ++rr) {
            int grow = bm + wm * 64 + i * 16 + kg4 * 4 + rr;
            float* dst = C + (size_t)grow * ldc + bn + wn * 64 + lrow;
#pragma unroll
            for (int j = 0; j < 4; ++j) {
                float v = acc[i][j][rr];
                if (EPI == 1) {
                    int gc = bn + wn * 64 + j * 16 + lrow;
                    v += (gc < nreal) ? bias[gc] : 0.f;
                    v = fmaxf(v, 0.f);
                }
                dst[j * 16] = v;
            }
        }
    }
}

// ---------------------------------------------------------------------------
// Layer-1 GEMM variant: A is fp32 [NN][lda] (x itself), split to hi/lo f16
// in-kernel (reg-staged ds_write); B pre-split f16 staged via gload16.
// ---------------------------------------------------------------------------
__global__ __launch_bounds__(256, 4) void mgemmA32_kernel(
    const float* __restrict__ A, int lda, int kreal,
    const _Float16* __restrict__ Bh, const _Float16* __restrict__ Bl,
    float* __restrict__ C, int ldc, int K, int nbn) {
    __shared__ __align__(16) _Float16 sAh[4096];
    __shared__ __align__(16) _Float16 sAl[4096];
    __shared__ __align__(16) _Float16 sBh[4096];
    __shared__ __align__(16) _Float16 sBl[4096];

    const int tid = (int)threadIdx.x;
    const int lane = tid & 63, w = tid >> 6;
    const int wm = w >> 1, wn = w & 1;
    const int lrow = lane & 15, kg4 = lane >> 4;

    const int wg = xcd_swizzle((int)blockIdx.x, (int)gridDim.x);
    const int bm = (wg / nbn) * 128;
    const int bn = (wg % nbn) * 128;

    f32v4 acc[4][4];
    const f32v4 zero4 = {0.f, 0.f, 0.f, 0.f};
#pragma unroll
    for (int i = 0; i < 4; ++i)
#pragma unroll
        for (int j = 0; j < 4; ++j) acc[i][j] = zero4;

    const int arow = tid & 127;          // A-stage row
    const int akg0 = (tid >> 7) << 1;    // A-stage kgrp base: 0 or 2
    const int gr = bm + arow;
    const bool rowok = (gr < NN);
    const float* arowp = A + (size_t)gr * lda;

    for (int k0 = 0; k0 < K; k0 += 32) {
        __syncthreads();
        // B: async global->LDS (f16 pre-split, Kpad so no guards)
#pragma unroll
        for (int p = 0; p < 2; ++p) {
            int c = p * 256 + w * 64 + lane;
            int kg = c >> 7, rw = c & 127;
            int ub = (p * 256 + w * 64) * 8;
            const size_t bo = (size_t)(bn + rw) * K + k0 + kg * 8;
            gload16(Bh + bo, &sBh[ub]);
            gload16(Bl + bo, &sBl[ub]);
        }
        // A: fp32 load -> hi/lo f16 -> LDS (overlaps with async B loads)
#pragma unroll
        for (int u = 0; u < 2; ++u) {
            int kg = akg0 + u;
            int gk = k0 + kg * 8;
            float v[8];
            if (rowok && gk + 8 <= kreal) {
#pragma unroll
                for (int q = 0; q < 4; ++q) {  // rows are 8B-aligned (lda=1022)
                    float2 t2 = *(const float2*)(arowp + gk + q * 2);
                    v[q * 2] = t2.x; v[q * 2 + 1] = t2.y;
                }
            } else {
#pragma unroll
                for (int q = 0; q < 8; ++q)
                    v[q] = (rowok && gk + q < kreal) ? arowp[gk + q] : 0.f;
            }
            f16v8 hv, lv;
#pragma unroll
            for (int q = 0; q < 8; ++q) {
                _Float16 h = (_Float16)v[q];
                hv[q] = h; lv[q] = (_Float16)(v[q] - (float)h);
            }
            *(f16v8*)&sAh[kg * 1024 + arow * 8] = hv;
            *(f16v8*)&sAl[kg * 1024 + arow * 8] = lv;
        }
        asm volatile("s_waitcnt vmcnt(0)" ::: "memory");
        __syncthreads();

        f16v8 ah[4], al[4];
#pragma unroll
        for (int i = 0; i < 4; ++i) {
            int rr = wm * 64 + i * 16 + lrow;
            ah[i] = *(const f16v8*)&sAh[kg4 * 1024 + rr * 8];
            al[i] = *(const f16v8*)&sAl[kg4 * 1024 + rr * 8];
        }
#pragma unroll
        for (int j = 0; j < 4; ++j) {
            int cc = wn * 64 + j * 16 + lrow;
            f16v8 bh = *(const f16v8*)&sBh[kg4 * 1024 + cc * 8];
            f16v8 bl = *(const f16v8*)&sBl[kg4 * 1024 + cc * 8];
#pragma unroll
            for (int i = 0; i < 4; ++i) {
                acc[i][j] = __builtin_amdgcn_mfma_f32_16x16x32_f16(ah[i], bh, acc[i][j], 0, 0, 0);
                acc[i][j] = __builtin_amdgcn_mfma_f32_16x16x32_f16(ah[i], bl, acc[i][j], 0, 0, 0);
                acc[i][j] = __builtin_amdgcn_mfma_f32_16x16x32_f16(al[i], bh, acc[i][j], 0, 0, 0);
            }
        }
    }

#pragma unroll
    for (int i = 0; i < 4; ++i) {
#pragma unroll
        for (int rr = 0; rr < 4; ++rr) {
            int grow = bm + wm * 64 + i * 16 + kg4 * 4 + rr;
            float* dst = C + (size_t)grow * ldc + bn + wn * 64 + lrow;
#pragma unroll
            for (int j = 0; j < 4; ++j) dst[j * 16] = acc[i][j][rr];
        }
    }
}

// ---------------------------------------------------------------------------
// fp32 SGEMM (head2 only). EPI: 1 = bias+relu, 2 = bias
// ---------------------------------------------------------------------------
template <int EPI>
__global__ __launch_bounds__(256) void sgemm_kernel(
    const float* __restrict__ A, int lda,
    const float* __restrict__ B, int ldb,
    const float* __restrict__ bias,
    float* __restrict__ C, int ldc,
    int M, int K, int N) {
    __shared__ float As[16 * 132];
    __shared__ float Bs[16 * 132];

    const int bm = blockIdx.x * 128;
    const int bn = blockIdx.y * 128;
    const int tid = (int)threadIdx.x;
    const int tm = tid >> 4;
    const int tn = tid & 15;

    float acc[8][8];
#pragma unroll
    for (int i = 0; i < 8; ++i)
#pragma unroll
        for (int j = 0; j < 8; ++j) acc[i][j] = 0.f;

    const int akk = tid & 15;
    const int ar0 = tid >> 4;
    const int bcol = tid & 127;
    const int bkr0 = tid >> 7;

    for (int k0 = 0; k0 < K; k0 += 16) {
        __syncthreads();
#pragma unroll
        for (int p = 0; p < 8; ++p) {
            int row = ar0 + p * 16;
            int grow = bm + row;
            int gk = k0 + akk;
            float v = (grow < M && gk < K) ? A[(size_t)grow * lda + gk] : 0.f;
            As[akk * 132 + row] = v;
        }
#pragma unroll
        for (int p = 0; p < 8; ++p) {
            int krow = bkr0 + p * 2;
            int gk = k0 + krow;
            int gcol = bn + bcol;
            float v = (gk < K && gcol < N) ? B[(size_t)gk * ldb + gcol] : 0.f;
            Bs[krow * 132 + bcol] = v;
        }
        __syncthreads();
#pragma unroll
        for (int kk = 0; kk < 16; ++kk) {
            float a[8], b[8];
            *(float4*)&a[0] = *(const float4*)&As[kk * 132 + tm * 8];
            *(float4*)&a[4] = *(const float4*)&As[kk * 132 + tm * 8 + 4];
            *(float4*)&b[0] = *(const float4*)&Bs[kk * 132 + tn * 8];
            *(float4*)&b[4] = *(const float4*)&Bs[kk * 132 + tn * 8 + 4];
#pragma unroll
            for (int i = 0; i < 8; ++i)
#pragma unroll
                for (int j = 0; j < 8; ++j)
                    acc[i][j] = fmaf(a[i], b[j], acc[i][j]);
        }
    }

#pragma unroll
    for (int i = 0; i < 8; ++i) {
        int r = bm + tm * 8 + i;
        if (r >= M) continue;
#pragma unroll
        for (int j = 0; j < 8; ++j) {
            int c = bn + tn * 8 + j;
            if (c >= N) continue;
            float v = acc[i][j];
            if (EPI >= 1) v += bias[c];
            if (EPI == 1) v = fmaxf(v, 0.f);
            C[(size_t)r * ldc + c] = v;
        }
    }
}

// ---------------------------------------------------------------------------
// CSR aggregation over 512 cols; writes relu(agg+bias) as hi/lo f16 split.
// one wave per node.
// ---------------------------------------------------------------------------
__global__ __launch_bounds__(256) void aggsplit_kernel(
    const float* __restrict__ tmp, const float* __restrict__ dinv,
    const int* __restrict__ row_ptr, const int* __restrict__ col_src,
    const float* __restrict__ bias,
    _Float16* __restrict__ oh, _Float16* __restrict__ ol, int ldo) {
    const int wid = (blockIdx.x * 256 + (int)threadIdx.x) >> 6;
    const int lane = (int)threadIdx.x & 63;
    if (wid >= NN) return;
    const float4* t4 = (const float4*)tmp;

    float di = dinv[wid];
    float wself = di * di;
    float4 acc[2];
    const float4* selfrow = t4 + (size_t)wid * 128;
#pragma unroll
    for (int v = 0; v < 2; ++v) {
        float4 x = selfrow[lane + 64 * v];
        acc[v].x = x.x * wself; acc[v].y = x.y * wself;
        acc[v].z = x.z * wself; acc[v].w = x.w * wself;
    }
    const int e0 = row_ptr[wid], e1 = row_ptr[wid + 1];
    for (int e = e0; e < e1; ++e) {
        int s = col_src[e];
        float ww = dinv[s] * di;
        const float4* r = t4 + (size_t)s * 128;
#pragma unroll
        for (int v = 0; v < 2; ++v) {
            float4 x = r[lane + 64 * v];
            acc[v].x = fmaf(x.x, ww, acc[v].x);
            acc[v].y = fmaf(x.y, ww, acc[v].y);
            acc[v].z = fmaf(x.z, ww, acc[v].z);
            acc[v].w = fmaf(x.w, ww, acc[v].w);
        }
    }
#pragma unroll
    for (int v = 0; v < 2; ++v) {
        int c0 = (lane + 64 * v) * 4;
        float4 b = *(const float4*)&bias[c0];
        float s0 = fmaxf(acc[v].x + b.x, 0.f);
        float s1 = fmaxf(acc[v].y + b.y, 0.f);
        float s2 = fmaxf(acc[v].z + b.z, 0.f);
        float s3 = fmaxf(acc[v].w + b.w, 0.f);
        f16v4 hv, lv;
        _Float16 h;
        h = (_Float16)s0; hv[0] = h; lv[0] = (_Float16)(s0 - (float)h);
        h = (_Float16)s1; hv[1] = h; lv[1] = (_Float16)(s1 - (float)h);
        h = (_Float16)s2; hv[2] = h; lv[2] = (_Float16)(s2 - (float)h);
        h = (_Float16)s3; hv[3] = h; lv[3] = (_Float16)(s3 - (float)h);
        *(f16v4*)&oh[(size_t)wid * ldo + c0] = hv;
        *(f16v4*)&ol[(size_t)wid * ldo + c0] = lv;
    }
}

// ---------------------------------------------------------------------------
// launch
// ---------------------------------------------------------------------------
static inline size_t ws_align(size_t x) { return (x + 255) & ~(size_t)255; }

extern "C" void kernel_launch(void* const* d_in, const int* in_sizes, int n_in,
                              void* d_out, int out_size, void* d_ws, size_t ws_size,
                              hipStream_t stream) {
    const float* x  = (const float*)d_in[0];
    const int* ei   = (const int*)d_in[1];
    const float* W1 = (const float*)d_in[2];  const float* b1 = (const float*)d_in[3];
    const float* W2 = (const float*)d_in[4];  const float* b2 = (const float*)d_in[5];
    const float* W3 = (const float*)d_in[6];  const float* b3 = (const float*)d_in[7];
    const float* W4 = (const float*)d_in[8];  const float* b4 = (const float*)d_in[9];
    const float* W5 = (const float*)d_in[10]; const float* b5 = (const float*)d_in[11];
    const float* Uw1 = (const float*)d_in[12]; const float* Ub1 = (const float*)d_in[13];
    const float* Uw2 = (const float*)d_in[14]; const float* Ub2 = (const float*)d_in[15];
    float* out = (float*)d_out;

    // workspace (~318 MB peak — matches round-3's proven footprint)
    char* ws = (char*)d_ws;
    float* dinv   = (float*)ws; ws += ws_align((size_t)NN * 4);
    int* cnt      = (int*)ws;   ws += ws_align((size_t)NN * 4);
    int* row_ptr  = (int*)ws;   ws += ws_align((size_t)(NN + 1) * 4);
    int* col_src  = (int*)ws;   ws += ws_align((size_t)NE * 4);
    _Float16* w1h = (_Float16*)ws; ws += ws_align((size_t)1024 * 1024 * 2);
    _Float16* w1l = (_Float16*)ws; ws += ws_align((size_t)1024 * 1024 * 2);
    _Float16* w2h = (_Float16*)ws; ws += ws_align((size_t)512 * 1024 * 2);
    _Float16* w2l = (_Float16*)ws; ws += ws_align((size_t)512 * 1024 * 2);
    _Float16* w3h = (_Float16*)ws; ws += ws_align((size_t)512 * 512 * 2);
    _Float16* w3l = (_Float16*)ws; ws += ws_align((size_t)512 * 512 * 2);
    _Float16* w4h = (_Float16*)ws; ws += ws_align((size_t)512 * 512 * 2);
    _Float16* w4l = (_Float16*)ws; ws += ws_align((size_t)512 * 512 * 2);
    _Float16* w5h = (_Float16*)ws; ws += ws_align((size_t)512 * 512 * 2);
    _Float16* w5l = (_Float16*)ws; ws += ws_align((size_t)512 * 512 * 2);
    _Float16* w6h = (_Float16*)ws; ws += ws_align((size_t)128 * 512 * 2);   // Uw1 pad N->128
    _Float16* w6l = (_Float16*)ws; ws += ws_align((size_t)128 * 512 * 2);
    _Float16* BIG = (_Float16*)ws; ws += (size_t)MPAD * 2048 * 2;  // 205 MB ping-pong
    float* T      = (float*)ws;    ws += (size_t)MPAD * 512 * 4;   // 102.5 MB fp32 gemm out

    // BIG slots (each MPAD*512 halves = 51.2 MB)
    _Float16* h1h = BIG;                         // MPAD x 1024 (slots 0-1)
    _Float16* h1l = BIG + (size_t)MPAD * 1024;   // MPAD x 1024 (slots 2-3)
    _Float16* hXh = BIG;                         // slot 0 (aliases h1h; h1 dead after L2 gemm)
    _Float16* hXl = BIG + (size_t)MPAD * 512;    // slot 1
    _Float16* hYh = BIG + (size_t)MPAD * 1024;   // slot 2
    _Float16* hYl = BIG + (size_t)MPAD * 1536;   // slot 3
    float* u1 = T;

    const int nb_n = (NN + 255) / 256;
    const int nb_e = (NE + 255) / 256;

    // CSR + norm build
    zero_int_kernel<<<nb_n, 256, 0, stream>>>(cnt, NN);
    init_deg_kernel<<<nb_n, 256, 0, stream>>>(dinv);
    hist_kernel<<<nb_e, 256, 0, stream>>>(ei, dinv, cnt);
    dinv_kernel<<<nb_n, 256, 0, stream>>>(dinv);
    scan_kernel<<<1, 1024, 0, stream>>>(cnt, row_ptr);
    zero_int_kernel<<<nb_n, 256, 0, stream>>>(cnt, NN);
    fill_kernel<<<nb_e, 256, 0, stream>>>(ei, row_ptr, cnt, col_src);

    // weight splits
    wsplit_kernel<<<(1024 * 1024 + 255) / 256, 256, 0, stream>>>(W1, w1h, w1l, 1022, 1024, 1024, 1024);
    wsplit_kernel<<<(512 * 1024 + 255) / 256, 256, 0, stream>>>(W2, w2h, w2l, 1024, 512, 1024, 512);
    wsplit_kernel<<<(512 * 512 + 255) / 256, 256, 0, stream>>>(W3, w3h, w3l, 512, 512, 512, 512);
    wsplit_kernel<<<(512 * 512 + 255) / 256, 256, 0, stream>>>(W4, w4h, w4l, 512, 512, 512, 512);
    wsplit_kernel<<<(512 * 512 + 255) / 256, 256, 0, stream>>>(W5, w5h, w5l, 512, 512, 512, 512);
    wsplit_kernel<<<(128 * 512 + 255) / 256, 256, 0, stream>>>(Uw1, w6h, w6l, 512, 75, 512, 128);

    const int agg_blocks = (NN + 3) / 4;
    const int g4 = 391 * 4;   // 128x128 tiles over MPAD x 512

    // L1 (A = fp32 x, K pad 1024 -> H1 1024) in two 512-col halves
    for (int c = 0; c < 2; ++c) {
        mgemmA32_kernel<<<g4, 256, 0, stream>>>(
            x, 1022, 1022, w1h + (size_t)c * 512 * 1024, w1l + (size_t)c * 512 * 1024,
            T, 512, 1024, 4);
        aggsplit_kernel<<<agg_blocks, 256, 0, stream>>>(
            T, dinv, row_ptr, col_src, b1 + c * 512, h1h + c * 512, h1l + c * 512, 1024);
    }
    // L2 (K=1024 -> 512); after this gemm h1 is dead, agg overwrites slots 0-1
    mgemm_kernel<0><<<g4, 256, 0, stream>>>(
        h1h, h1l, 1024, w2h, w2l, nullptr, 0, T, 512, 1024, 4);
    aggsplit_kernel<<<agg_blocks, 256, 0, stream>>>(
        T, dinv, row_ptr, col_src, b2, hXh, hXl, 512);
    // L3
    mgemm_kernel<0><<<g4, 256, 0, stream>>>(
        hXh, hXl, 512, w3h, w3l, nullptr, 0, T, 512, 512, 4);
    aggsplit_kernel<<<agg_blocks, 256, 0, stream>>>(
        T, dinv, row_ptr, col_src, b3, hYh, hYl, 512);
    // L4
    mgemm_kernel<0><<<g4, 256, 0, stream>>>(
        hYh, hYl, 512, w4h, w4l, nullptr, 0, T, 512, 512, 4);
    aggsplit_kernel<<<agg_blocks, 256, 0, stream>>>(
        T, dinv, row_ptr, col_src, b4, hXh, hXl, 512);
    // L5
    mgemm_kernel<0><<<g4, 256, 0, stream>>>(
        hXh, hXl, 512, w5h, w5l, nullptr, 0, T, 512, 512, 4);
    aggsplit_kernel<<<agg_blocks, 256, 0, stream>>>(
        T, dinv, row_ptr, col_src, b5, hYh, hYl, 512);
    // head1: relu(h5 @ Uw1 + Ub1) -> u1 [MPAD x 128] (reads slots 2-3, writes T)
    mgemm_kernel<1><<<391, 256, 0, stream>>>(
        hYh, hYl, 512, w6h, w6l, Ub1, 75, u1, 128, 512, 1);
    // head2: u1 @ Uw2 + Ub2 -> out (K=75, N=11)
    sgemm_kernel<2><<<dim3(391, 1), 256, 0, stream>>>(
        u1, 128, Uw2, 11, Ub2, out, 11, NN, 75, 11);
}